// Round 2
// baseline (622.718 us; speedup 1.0000x reference)
//
#include <hip/hip_runtime.h>

typedef __attribute__((ext_vector_type(8))) short short8;
typedef __attribute__((ext_vector_type(4))) float f32x4;

#define B_SZ 32
#define C_IN 512
#define C8V 64
#define LSEQ 1024
#define OUT_ELEMS (B_SZ * C_IN * LSEQ)   // 16777216

__device__ inline unsigned short bf16_rn(float f) {
  unsigned int u = __float_as_uint(f);
  unsigned int r = 0x7FFFu + ((u >> 16) & 1u);
  return (unsigned short)((u + r) >> 16);
}
__device__ inline float bf16_to_f32(unsigned short h) {
  return __uint_as_float(((unsigned int)h) << 16);
}
__device__ inline void split_bf16(float f, unsigned short &hi, unsigned short &lo) {
  hi = bf16_rn(f);
  lo = bf16_rn(f - bf16_to_f32(hi));
}

// ---------------- Kernel 1: QKV projection ----------------
// grid (16 l-tiles, 10 row-tiles, B). rows: [0]=q(64), [1]=k(64), [2..9]=v(512)
__global__ __launch_bounds__(256) void qkv_proj(
    const float* __restrict__ x,
    const float* __restrict__ Wq, const float* __restrict__ bq,
    const float* __restrict__ Wk, const float* __restrict__ bk,
    const float* __restrict__ Wv, const float* __restrict__ bv,
    float* __restrict__ qws, float* __restrict__ kws,
    unsigned short* __restrict__ vws)
{
  const int lt = blockIdx.x;
  const int rt = blockIdx.y;
  const int b  = blockIdx.z;
  const int tid = threadIdx.x;

  const float* W; const float* bias; int row0; bool split;
  if (rt == 0)      { W = Wq; bias = bq; row0 = 0;           split = true;  }
  else if (rt == 1) { W = Wk; bias = bk; row0 = 0;           split = true;  }
  else              { W = Wv; bias = bv; row0 = (rt-2)*64;   split = false; }

  __shared__ short Ah[64][40]; __shared__ short Al[64][40];
  __shared__ short Bh[64][40]; __shared__ short Bl[64][40];

  const int wave = tid >> 6, lane = tid & 63;
  const int wr = wave >> 1, wc = wave & 1;
  const int g = lane >> 4, ln = lane & 15;
  const int k0g = g * 8;

  f32x4 acc[2][2] = {};
  const long xbase = (long)b * C_IN * LSEQ + (long)lt * 64;

  for (int kb = 0; kb < C_IN / 32; ++kb) {
    #pragma unroll
    for (int i = 0; i < 8; ++i) {            // W tile [64 r][32 k]
      int idx = tid + i * 256;
      int r = idx >> 5, kk = idx & 31;
      float f = W[(long)(row0 + r) * C_IN + kb * 32 + kk];
      unsigned short hi, lo; split_bf16(f, hi, lo);
      Ah[r][kk] = (short)hi; Al[r][kk] = (short)lo;
    }
    #pragma unroll
    for (int i = 0; i < 8; ++i) {            // x tile [32 k][64 l] -> LDS [l][k]
      int idx = tid + i * 256;
      int kk = idx >> 6, ll = idx & 63;
      float f = x[xbase + (long)(kb * 32 + kk) * LSEQ + ll];
      unsigned short hi, lo; split_bf16(f, hi, lo);
      Bh[ll][kk] = (short)hi; Bl[ll][kk] = (short)lo;
    }
    __syncthreads();
    #pragma unroll
    for (int mi = 0; mi < 2; ++mi)
      #pragma unroll
      for (int ni = 0; ni < 2; ++ni) {
        short8 ah = *(const short8*)&Ah[wr*32 + mi*16 + ln][k0g];
        short8 bh = *(const short8*)&Bh[wc*32 + ni*16 + ln][k0g];
        acc[mi][ni] = __builtin_amdgcn_mfma_f32_16x16x32_bf16(ah, bh, acc[mi][ni], 0,0,0);
        if (split) {
          short8 al = *(const short8*)&Al[wr*32 + mi*16 + ln][k0g];
          short8 bl = *(const short8*)&Bl[wc*32 + ni*16 + ln][k0g];
          acc[mi][ni] = __builtin_amdgcn_mfma_f32_16x16x32_bf16(ah, bl, acc[mi][ni], 0,0,0);
          acc[mi][ni] = __builtin_amdgcn_mfma_f32_16x16x32_bf16(al, bh, acc[mi][ni], 0,0,0);
        }
      }
    __syncthreads();
  }

  #pragma unroll
  for (int mi = 0; mi < 2; ++mi)
    #pragma unroll
    for (int ni = 0; ni < 2; ++ni)
      #pragma unroll
      for (int j = 0; j < 4; ++j) {
        int rloc = wr*32 + mi*16 + g*4 + j;
        int cloc = wc*32 + ni*16 + ln;
        int grow = row0 + rloc;
        float val = acc[mi][ni][j] + bias[grow];
        int l = lt*64 + cloc;
        if (rt == 0)      qws[((long)b*C8V + grow)*LSEQ + l] = val;
        else if (rt == 1) kws[((long)b*C8V + grow)*LSEQ + l] = val;
        else              vws[((long)b*C_IN + grow)*LSEQ + l] = bf16_rn(val);
      }
}

// ---------------- Kernel 2: energy + softmax + attention write ----------------
// grid (64 l-tiles of 16, B). Full m=1024 resident in registers per block.
__global__ __launch_bounds__(256) void energy_softmax(
    const float* __restrict__ qws, const float* __restrict__ kws,
    float* __restrict__ attn)
{
  const int lt = blockIdx.x;
  const int b  = blockIdx.y;
  const int tid = threadIdx.x;
  const int wave = tid >> 6, lane = tid & 63;
  const int g = lane >> 4, ln = lane & 15;

  __shared__ short Qh[16][72]; __shared__ short Ql[16][72];
  __shared__ short Kh[128][72]; __shared__ short Kl[128][72];
  __shared__ float redM[4][16]; __shared__ float redS[4][16];

  for (int i = 0; i < 4; ++i) {        // q tile -> LDS [l][d], split
    int idx = tid + i * 256;           // 1024 = 64*16
    int d = idx >> 4, ll = idx & 15;
    float f = qws[((long)b*C8V + d)*LSEQ + lt*16 + ll];
    unsigned short hi, lo; split_bf16(f, hi, lo);
    Qh[ll][d] = (short)hi; Ql[ll][d] = (short)lo;
  }
  __syncthreads();

  short8 ah[2], al[2];
  #pragma unroll
  for (int ks = 0; ks < 2; ++ks) {
    ah[ks] = *(const short8*)&Qh[ln][ks*32 + g*8];
    al[ks] = *(const short8*)&Ql[ln][ks*32 + g*8];
  }

  f32x4 acc[8][2] = {};
  for (int c = 0; c < 8; ++c) {
    if (c) __syncthreads();
    for (int i = 0; i < 32; ++i) {     // K chunk [64 d][128 m] -> LDS [m][d], split
      int idx = tid + i * 256;         // 8192
      int d = idx >> 7, mm = idx & 127;
      float f = kws[((long)b*C8V + d)*LSEQ + c*128 + mm];
      unsigned short hi, lo; split_bf16(f, hi, lo);
      Kh[mm][d] = (short)hi; Kl[mm][d] = (short)lo;
    }
    __syncthreads();
    #pragma unroll
    for (int fq = 0; fq < 2; ++fq) {
      int mloc = wave*32 + fq*16 + ln;
      #pragma unroll
      for (int ks = 0; ks < 2; ++ks) {
        short8 bh = *(const short8*)&Kh[mloc][ks*32 + g*8];
        short8 bl = *(const short8*)&Kl[mloc][ks*32 + g*8];
        acc[c][fq] = __builtin_amdgcn_mfma_f32_16x16x32_bf16(ah[ks], bh, acc[c][fq], 0,0,0);
        acc[c][fq] = __builtin_amdgcn_mfma_f32_16x16x32_bf16(ah[ks], bl, acc[c][fq], 0,0,0);
        acc[c][fq] = __builtin_amdgcn_mfma_f32_16x16x32_bf16(al[ks], bh, acc[c][fq], 0,0,0);
      }
    }
  }

  // --- row softmax (rows r = g*4+j local; cols spread over 16 lanes x 16 frags)
  float mx[4];
  #pragma unroll
  for (int j = 0; j < 4; ++j) {
    float m = -1e30f;
    for (int c = 0; c < 8; ++c) for (int fq = 0; fq < 2; ++fq) m = fmaxf(m, acc[c][fq][j]);
    for (int off = 1; off < 16; off <<= 1) m = fmaxf(m, __shfl_xor(m, off));
    mx[j] = m;
  }
  if (ln == 0) { for (int j = 0; j < 4; ++j) redM[wave][g*4+j] = mx[j]; }
  __syncthreads();
  #pragma unroll
  for (int j = 0; j < 4; ++j) {
    float m = redM[0][g*4+j];
    for (int w = 1; w < 4; ++w) m = fmaxf(m, redM[w][g*4+j]);
    mx[j] = m;
  }
  float sm[4];
  #pragma unroll
  for (int j = 0; j < 4; ++j) {
    float s = 0.f;
    for (int c = 0; c < 8; ++c) for (int fq = 0; fq < 2; ++fq) {
      float p = expf(acc[c][fq][j] - mx[j]);
      acc[c][fq][j] = p;
      s += p;
    }
    for (int off = 1; off < 16; off <<= 1) s += __shfl_xor(s, off);
    sm[j] = s;
  }
  if (ln == 0) { for (int j = 0; j < 4; ++j) redS[wave][g*4+j] = sm[j]; }
  __syncthreads();
  #pragma unroll
  for (int j = 0; j < 4; ++j) {
    float s = redS[0][g*4+j];
    for (int w = 1; w < 4; ++w) s += redS[w][g*4+j];
    sm[j] = 1.0f / s;
  }
  for (int c = 0; c < 8; ++c)
    for (int fq = 0; fq < 2; ++fq) {
      int m0 = c*128 + wave*32 + fq*16 + ln;
      #pragma unroll
      for (int j = 0; j < 4; ++j) {
        int r = g*4 + j;
        attn[((long)b*LSEQ + lt*16 + r)*LSEQ + m0] = acc[c][fq][j] * sm[j];
      }
    }
}

// ---------------- Kernel 3: out = gamma * (V @ Attn^T) + x ----------------
__global__ __launch_bounds__(256) void pv_out(
    const unsigned short* __restrict__ vws,
    const float* __restrict__ attn,
    const float* __restrict__ x,
    const float* __restrict__ gamma,
    float* __restrict__ out)
{
  const int lt = blockIdx.x;   // 16 tiles of 64 l
  const int ct = blockIdx.y;   // 8 tiles of 64 c
  const int b  = blockIdx.z;
  const int tid = threadIdx.x;
  const int wave = tid >> 6, lane = tid & 63;
  const int wr = wave >> 1, wc = wave & 1;
  const int g = lane >> 4, ln = lane & 15, k0g = g*8;

  __shared__ short Vh[64][40];
  __shared__ short Ph[64][40];

  f32x4 acc[2][2] = {};

  for (int kb = 0; kb < LSEQ/32; ++kb) {
    #pragma unroll
    for (int i = 0; i < 8; ++i) {      // V tile [64 c][32 m] (already bf16)
      int idx = tid + i*256;
      int r = idx >> 5, kk = idx & 31;
      Vh[r][kk] = (short)vws[((long)b*C_IN + ct*64 + r)*LSEQ + kb*32 + kk];
    }
    #pragma unroll
    for (int i = 0; i < 8; ++i) {      // attn tile [64 l][32 m] f32 -> bf16
      int idx = tid + i*256;
      int ll = idx >> 5, kk = idx & 31;
      float f = attn[((long)b*LSEQ + lt*64 + ll)*LSEQ + kb*32 + kk];
      Ph[ll][kk] = (short)bf16_rn(f);
    }
    __syncthreads();
    #pragma unroll
    for (int mi = 0; mi < 2; ++mi)
      #pragma unroll
      for (int ni = 0; ni < 2; ++ni) {
        short8 a  = *(const short8*)&Vh[wr*32 + mi*16 + ln][k0g];
        short8 bb = *(const short8*)&Ph[wc*32 + ni*16 + ln][k0g];
        acc[mi][ni] = __builtin_amdgcn_mfma_f32_16x16x32_bf16(a, bb, acc[mi][ni], 0,0,0);
      }
    __syncthreads();
  }

  float gm = gamma[0];
  #pragma unroll
  for (int mi = 0; mi < 2; ++mi)
    #pragma unroll
    for (int ni = 0; ni < 2; ++ni)
      #pragma unroll
      for (int j = 0; j < 4; ++j) {
        int c = ct*64 + wr*32 + mi*16 + g*4 + j;
        int l = lt*64 + wc*32 + ni*16 + ln;
        long idx = ((long)b*C_IN + c)*LSEQ + l;
        out[idx] = gm * acc[mi][ni][j] + x[idx];
      }
}

extern "C" void kernel_launch(void* const* d_in, const int* in_sizes, int n_in,
                              void* d_out, int out_size, void* d_ws, size_t ws_size,
                              hipStream_t stream)
{
  const float* x  = (const float*)d_in[0];
  const float* Wq = (const float*)d_in[1];
  const float* bq = (const float*)d_in[2];
  const float* Wk = (const float*)d_in[3];
  const float* bk = (const float*)d_in[4];
  const float* Wv = (const float*)d_in[5];
  const float* bv = (const float*)d_in[6];
  const float* gamma = (const float*)d_in[7];
  float* out  = (float*)d_out;
  float* attn = out + OUT_ELEMS;

  char* ws = (char*)d_ws;
  float* qws = (float*)ws;                                        // 8 MiB
  float* kws = (float*)(ws + (size_t)B_SZ*C8V*LSEQ*4);            // 8 MiB
  unsigned short* vws = (unsigned short*)(ws + 2*(size_t)B_SZ*C8V*LSEQ*4); // 32 MiB

  qkv_proj<<<dim3(16,10,B_SZ), 256, 0, stream>>>(x, Wq, bq, Wk, bk, Wv, bv, qws, kws, vws);
  energy_softmax<<<dim3(64,B_SZ), 256, 0, stream>>>(qws, kws, attn);
  pv_out<<<dim3(16,8,B_SZ), 256, 0, stream>>>(vws, attn, x, gamma, out);
}

// Round 3
// 320.675 us; speedup vs baseline: 1.9419x; 1.9419x over previous
//
#include <hip/hip_runtime.h>

typedef __attribute__((ext_vector_type(8))) short short8;
typedef __attribute__((ext_vector_type(4))) short short4v;
typedef __attribute__((ext_vector_type(4))) float f32x4;

#define B_SZ 32
#define C_IN 512
#define C8V 64
#define LSEQ 1024
#define OUT_ELEMS (B_SZ * C_IN * LSEQ)

__device__ inline unsigned short bf16_rn(float f) {
  unsigned int u = __float_as_uint(f);
  unsigned int r = 0x7FFFu + ((u >> 16) & 1u);
  return (unsigned short)((u + r) >> 16);
}
__device__ inline float bf16_to_f32(unsigned short h) {
  return __uint_as_float(((unsigned int)h) << 16);
}
__device__ inline void split_bf16(float f, unsigned short &hi, unsigned short &lo) {
  hi = bf16_rn(f);
  lo = bf16_rn(f - bf16_to_f32(hi));
}

// ---------- Kernel 0: pre-split weights into bf16 hi/lo planes (once) ----------
__global__ __launch_bounds__(256) void split_weights(
    const float* __restrict__ Wq, const float* __restrict__ Wk, const float* __restrict__ Wv,
    unsigned short* __restrict__ Wqh, unsigned short* __restrict__ Wql,
    unsigned short* __restrict__ Wkh, unsigned short* __restrict__ Wkl,
    unsigned short* __restrict__ Wvh)
{
  int i = (blockIdx.x * 256 + threadIdx.x) * 4;
  if (i < 262144) {
    f32x4 f = *(const f32x4*)&Wv[i];
    #pragma unroll
    for (int j = 0; j < 4; ++j) Wvh[i + j] = bf16_rn(f[j]);
  } else if (i < 294912) {
    int k = i - 262144;
    f32x4 f = *(const f32x4*)&Wq[k];
    #pragma unroll
    for (int j = 0; j < 4; ++j) { unsigned short h, l; split_bf16(f[j], h, l); Wqh[k+j] = h; Wql[k+j] = l; }
  } else {
    int k = i - 294912;
    f32x4 f = *(const f32x4*)&Wk[k];
    #pragma unroll
    for (int j = 0; j < 4; ++j) { unsigned short h, l; split_bf16(f[j], h, l); Wkh[k+j] = h; Wkl[k+j] = l; }
  }
}

// ---------- Kernel 1: q,k projection -> pre-split [b][l][64] hi/lo planes ----------
// tile: M=128 (64 q rows + 64 k rows) x N=64 l, K-step 64. grid (16 nt, 32 b).
__global__ __launch_bounds__(256) void qk_proj(
    const float* __restrict__ x,
    const unsigned short* __restrict__ Wqh, const unsigned short* __restrict__ Wql,
    const unsigned short* __restrict__ Wkh, const unsigned short* __restrict__ Wkl,
    const float* __restrict__ bq, const float* __restrict__ bk,
    unsigned short* __restrict__ qh, unsigned short* __restrict__ ql,
    unsigned short* __restrict__ kh, unsigned short* __restrict__ kl)
{
  const int nt = blockIdx.x;
  const int b  = blockIdx.y;
  const int tid = threadIdx.x;
  const int wave = tid >> 6, lane = tid & 63;
  const int wr = wave >> 1, wc = wave & 1;
  const int g = lane >> 4, ln = lane & 15;

  __shared__ char smem[66560];
  unsigned short* Ah = (unsigned short*)smem;      // [128][64] swizzled
  unsigned short* Al = Ah + 128*64;
  unsigned short* Bh = Al + 128*64;                // [64][64] swizzled
  unsigned short* Bl = Bh + 64*64;
  float* xs = (float*)(Bl + 64*64);                // [64][68] f32 scratch

  f32x4 acc[4][2] = {};

  for (int kb = 0; kb < 8; ++kb) {
    if (kb) __syncthreads();
    #pragma unroll
    for (int i = 0; i < 4; ++i) {                  // A planes (pre-split W)
      int idx = tid + i*256;
      int r = idx >> 3, jj = idx & 7;
      const unsigned short* sH = (r < 64) ? &Wqh[r*512 + kb*64 + jj*8]
                                          : &Wkh[(r-64)*512 + kb*64 + jj*8];
      const unsigned short* sL = (r < 64) ? &Wql[r*512 + kb*64 + jj*8]
                                          : &Wkl[(r-64)*512 + kb*64 + jj*8];
      int dst = r*64 + ((jj ^ (r & 7)) << 3);
      *(short8*)&Ah[dst] = *(const short8*)sH;
      *(short8*)&Al[dst] = *(const short8*)sL;
    }
    #pragma unroll
    for (int i = 0; i < 4; ++i) {                  // x chunk [64 k][64 l] -> f32 scratch
      int idx = tid + i*256;
      int kk = idx >> 4, l4 = idx & 15;
      f32x4 v = *(const f32x4*)&x[((long)b*C_IN + kb*64 + kk)*LSEQ + nt*64 + l4*4];
      *(f32x4*)&xs[kk*68 + l4*4] = v;
    }
    __syncthreads();
    {                                              // transpose + split -> B planes
      int l = tid & 63, kc = (tid >> 6) * 16;
      unsigned short hbuf[16], lbuf[16];
      #pragma unroll
      for (int i = 0; i < 16; ++i) split_bf16(xs[(kc + i)*68 + l], hbuf[i], lbuf[i]);
      #pragma unroll
      for (int s2 = 0; s2 < 2; ++s2) {
        int s = (kc >> 3) + s2;
        int dst = l*64 + ((s ^ (l & 7)) << 3);
        *(short8*)&Bh[dst] = *(const short8*)&hbuf[s2*8];
        *(short8*)&Bl[dst] = *(const short8*)&lbuf[s2*8];
      }
    }
    __syncthreads();
    #pragma unroll
    for (int ks = 0; ks < 2; ++ks) {
      short8 bhf[2], blf[2];
      #pragma unroll
      for (int ni = 0; ni < 2; ++ni) {
        int cr = wc*32 + ni*16 + ln;
        int s = ((ks*4 + g) ^ (cr & 7)) << 3;
        bhf[ni] = *(const short8*)&Bh[cr*64 + s];
        blf[ni] = *(const short8*)&Bl[cr*64 + s];
      }
      #pragma unroll
      for (int mi = 0; mi < 4; ++mi) {
        int ar = wr*64 + mi*16 + ln;
        int s = ((ks*4 + g) ^ (ar & 7)) << 3;
        short8 ahf = *(const short8*)&Ah[ar*64 + s];
        short8 alf = *(const short8*)&Al[ar*64 + s];
        #pragma unroll
        for (int ni = 0; ni < 2; ++ni) {
          acc[mi][ni] = __builtin_amdgcn_mfma_f32_16x16x32_bf16(ahf, bhf[ni], acc[mi][ni], 0,0,0);
          acc[mi][ni] = __builtin_amdgcn_mfma_f32_16x16x32_bf16(ahf, blf[ni], acc[mi][ni], 0,0,0);
          acc[mi][ni] = __builtin_amdgcn_mfma_f32_16x16x32_bf16(alf, bhf[ni], acc[mi][ni], 0,0,0);
        }
      }
    }
  }
  __syncthreads();
  // epilogue: bias + split -> Tr [64 l][136], then coalesced [b][l][64] stores
  unsigned short* Trh = (unsigned short*)smem;
  unsigned short* Trl = Trh + 64*136;
  #pragma unroll
  for (int mi = 0; mi < 4; ++mi)
    #pragma unroll
    for (int ni = 0; ni < 2; ++ni)
      #pragma unroll
      for (int j = 0; j < 4; ++j) {
        int rloc = wr*64 + mi*16 + g*4 + j;
        int cloc = wc*32 + ni*16 + ln;
        float bias = (rloc < 64) ? bq[rloc] : bk[rloc - 64];
        unsigned short hi, lo; split_bf16(acc[mi][ni][j] + bias, hi, lo);
        Trh[cloc*136 + rloc] = hi;
        Trl[cloc*136 + rloc] = lo;
      }
  __syncthreads();
  #pragma unroll
  for (int i = 0; i < 4; ++i) {
    int idx = tid + i*256;
    int l = idx >> 4, s = idx & 15;
    long row = ((long)b*LSEQ + nt*64 + l) * 64;
    short8 h  = *(const short8*)&Trh[l*136 + s*8];
    short8 lo = *(const short8*)&Trl[l*136 + s*8];
    if (s < 8) { *(short8*)&qh[row + s*8] = h;      *(short8*)&ql[row + s*8] = lo; }
    else       { *(short8*)&kh[row + (s-8)*8] = h;  *(short8*)&kl[row + (s-8)*8] = lo; }
  }
}

// ---------- Kernel 2: v projection -> bf16 [b][c][l] ----------
// tile 128c x 128l, K-step 64. grid (8 lt, 4 ct, 32 b).
__global__ __launch_bounds__(256) void v_proj(
    const float* __restrict__ x,
    const unsigned short* __restrict__ Wvh,
    const float* __restrict__ bv,
    unsigned short* __restrict__ vws)
{
  const int lt = blockIdx.x;
  const int ct = blockIdx.y;
  const int b  = blockIdx.z;
  const int tid = threadIdx.x;
  const int wave = tid >> 6, lane = tid & 63;
  const int wr = wave >> 1, wc = wave & 1;
  const int g = lane >> 4, ln = lane & 15;

  __shared__ char smem[66560];
  unsigned short* Ahs = (unsigned short*)smem;     // [128][64] swizzled
  unsigned short* Bhs = Ahs + 8192;                // [128][64] swizzled
  float* xs = (float*)(Bhs + 8192);                // [64][132] f32 scratch

  f32x4 acc[4][4] = {};

  for (int kb = 0; kb < 8; ++kb) {
    if (kb) __syncthreads();
    #pragma unroll
    for (int i = 0; i < 4; ++i) {                  // A = Wv rows
      int idx = tid + i*256;
      int r = idx >> 3, jj = idx & 7;
      *(short8*)&Ahs[r*64 + ((jj ^ (r & 7)) << 3)] =
        *(const short8*)&Wvh[(ct*128 + r)*512 + kb*64 + jj*8];
    }
    #pragma unroll
    for (int i = 0; i < 8; ++i) {                  // x chunk [64 k][128 l]
      int idx = tid + i*256;
      int kk = idx >> 5, l4 = idx & 31;
      f32x4 v = *(const f32x4*)&x[((long)b*C_IN + kb*64 + kk)*LSEQ + lt*128 + l4*4];
      *(f32x4*)&xs[kk*132 + l4*4] = v;
    }
    __syncthreads();
    {                                              // transpose -> B plane (hi only)
      int l = tid & 127, kc = (tid >> 7) * 32;
      unsigned short hbuf[32];
      #pragma unroll
      for (int i = 0; i < 32; ++i) hbuf[i] = bf16_rn(xs[(kc + i)*132 + l]);
      #pragma unroll
      for (int s2 = 0; s2 < 4; ++s2) {
        int s = (kc >> 3) + s2;
        *(short8*)&Bhs[l*64 + ((s ^ (l & 7)) << 3)] = *(const short8*)&hbuf[s2*8];
      }
    }
    __syncthreads();
    #pragma unroll
    for (int ks = 0; ks < 2; ++ks) {
      short8 bf[4];
      #pragma unroll
      for (int ni = 0; ni < 4; ++ni) {
        int cr = wc*64 + ni*16 + ln;
        bf[ni] = *(const short8*)&Bhs[cr*64 + (((ks*4 + g) ^ (cr & 7)) << 3)];
      }
      #pragma unroll
      for (int mi = 0; mi < 4; ++mi) {
        int ar = wr*64 + mi*16 + ln;
        short8 af = *(const short8*)&Ahs[ar*64 + (((ks*4 + g) ^ (ar & 7)) << 3)];
        #pragma unroll
        for (int ni = 0; ni < 4; ++ni)
          acc[mi][ni] = __builtin_amdgcn_mfma_f32_16x16x32_bf16(af, bf[ni], acc[mi][ni], 0,0,0);
      }
    }
  }
  __syncthreads();
  unsigned short* Tr = (unsigned short*)smem;      // [128 c][136]
  #pragma unroll
  for (int mi = 0; mi < 4; ++mi)
    #pragma unroll
    for (int ni = 0; ni < 4; ++ni)
      #pragma unroll
      for (int j = 0; j < 4; ++j) {
        int rloc = wr*64 + mi*16 + g*4 + j;
        int cloc = wc*64 + ni*16 + ln;
        Tr[rloc*136 + cloc] = bf16_rn(acc[mi][ni][j] + bv[ct*128 + rloc]);
      }
  __syncthreads();
  #pragma unroll
  for (int i = 0; i < 8; ++i) {
    int idx = tid + i*256;
    int c = idx >> 4, s = idx & 15;
    *(short8*)&vws[((long)b*C_IN + ct*128 + c)*LSEQ + lt*128 + s*8] =
      *(const short8*)&Tr[c*136 + s*8];
  }
}

// ---------- Kernel 3: energy + softmax -> attention (f32, d_out) ----------
__global__ __launch_bounds__(256) void energy_softmax(
    const unsigned short* __restrict__ qh, const unsigned short* __restrict__ ql,
    const unsigned short* __restrict__ kh, const unsigned short* __restrict__ kl,
    float* __restrict__ attn)
{
  const int lt = blockIdx.x;
  const int b  = blockIdx.y;
  const int tid = threadIdx.x;
  const int wave = tid >> 6, lane = tid & 63;
  const int g = lane >> 4, ln = lane & 15;

  __shared__ unsigned short Kh[128*64];
  __shared__ unsigned short Kl[128*64];
  __shared__ float redM[4][16];
  __shared__ float redS[4][16];

  short8 ah[2], al[2];
  {
    long qrow = ((long)b*LSEQ + lt*16 + ln) * 64;
    #pragma unroll
    for (int ks = 0; ks < 2; ++ks) {
      ah[ks] = *(const short8*)&qh[qrow + ks*32 + g*8];
      al[ks] = *(const short8*)&ql[qrow + ks*32 + g*8];
    }
  }

  f32x4 acc[8][2] = {};
  for (int c = 0; c < 8; ++c) {
    if (c) __syncthreads();
    #pragma unroll
    for (int i = 0; i < 4; ++i) {
      int idx = tid + i*256;
      int r = idx >> 3, jj = idx & 7;
      long src = ((long)b*LSEQ + c*128 + r) * 64 + jj*8;
      int dst = r*64 + ((jj ^ (r & 7)) << 3);
      *(short8*)&Kh[dst] = *(const short8*)&kh[src];
      *(short8*)&Kl[dst] = *(const short8*)&kl[src];
    }
    __syncthreads();
    #pragma unroll
    for (int fq = 0; fq < 2; ++fq) {
      int mloc = wave*32 + fq*16 + ln;
      #pragma unroll
      for (int ks = 0; ks < 2; ++ks) {
        int s = ((ks*4 + g) ^ (mloc & 7)) << 3;
        short8 bh = *(const short8*)&Kh[mloc*64 + s];
        short8 bl = *(const short8*)&Kl[mloc*64 + s];
        acc[c][fq] = __builtin_amdgcn_mfma_f32_16x16x32_bf16(ah[ks], bh, acc[c][fq], 0,0,0);
        acc[c][fq] = __builtin_amdgcn_mfma_f32_16x16x32_bf16(ah[ks], bl, acc[c][fq], 0,0,0);
        acc[c][fq] = __builtin_amdgcn_mfma_f32_16x16x32_bf16(al[ks], bh, acc[c][fq], 0,0,0);
      }
    }
  }

  float mx[4];
  #pragma unroll
  for (int j = 0; j < 4; ++j) {
    float m = -1e30f;
    for (int c = 0; c < 8; ++c) for (int fq = 0; fq < 2; ++fq) m = fmaxf(m, acc[c][fq][j]);
    for (int off = 1; off < 16; off <<= 1) m = fmaxf(m, __shfl_xor(m, off));
    mx[j] = m;
  }
  if (ln == 0) { for (int j = 0; j < 4; ++j) redM[wave][g*4+j] = mx[j]; }
  __syncthreads();
  #pragma unroll
  for (int j = 0; j < 4; ++j) {
    float m = redM[0][g*4+j];
    for (int w = 1; w < 4; ++w) m = fmaxf(m, redM[w][g*4+j]);
    mx[j] = m;
  }
  float sm[4];
  #pragma unroll
  for (int j = 0; j < 4; ++j) {
    float s = 0.f;
    for (int c = 0; c < 8; ++c) for (int fq = 0; fq < 2; ++fq) {
      float p = expf(acc[c][fq][j] - mx[j]);
      acc[c][fq][j] = p;
      s += p;
    }
    for (int off = 1; off < 16; off <<= 1) s += __shfl_xor(s, off);
    sm[j] = s;
  }
  if (ln == 0) { for (int j = 0; j < 4; ++j) redS[wave][g*4+j] = sm[j]; }
  __syncthreads();
  #pragma unroll
  for (int j = 0; j < 4; ++j) {
    float s = redS[0][g*4+j];
    for (int w = 1; w < 4; ++w) s += redS[w][g*4+j];
    sm[j] = 1.0f / s;
  }
  for (int c = 0; c < 8; ++c)
    for (int fq = 0; fq < 2; ++fq) {
      int m0 = c*128 + wave*32 + fq*16 + ln;
      #pragma unroll
      for (int j = 0; j < 4; ++j)
        attn[((long)b*LSEQ + lt*16 + g*4 + j)*LSEQ + m0] = acc[c][fq][j] * sm[j];
    }
}

// ---------- Kernel 4: out = gamma * (V @ Attn^T) + x ----------
// tile 128c x 128l, m-step 64. grid (8 lt, 4 ct, 32 b).
__global__ __launch_bounds__(256) void pv_out(
    const unsigned short* __restrict__ vws,
    const float* __restrict__ attn,
    const float* __restrict__ x,
    const float* __restrict__ gamma,
    float* __restrict__ out)
{
  const int lt = blockIdx.x;
  const int ct = blockIdx.y;
  const int b  = blockIdx.z;
  const int tid = threadIdx.x;
  const int wave = tid >> 6, lane = tid & 63;
  const int wr = wave >> 1, wc = wave & 1;
  const int g = lane >> 4, ln = lane & 15;

  __shared__ char smem[34816];
  unsigned short* Vh = (unsigned short*)smem;      // [128][64] swizzled
  unsigned short* Ph = Vh + 8192;                  // [128][64] swizzled

  f32x4 acc[4][4] = {};

  for (int mb = 0; mb < 16; ++mb) {
    if (mb) __syncthreads();
    #pragma unroll
    for (int i = 0; i < 4; ++i) {                  // V tile
      int idx = tid + i*256;
      int r = idx >> 3, jj = idx & 7;
      *(short8*)&Vh[r*64 + ((jj ^ (r & 7)) << 3)] =
        *(const short8*)&vws[((long)b*C_IN + ct*128 + r)*LSEQ + mb*64 + jj*8];
    }
    #pragma unroll
    for (int i = 0; i < 8; ++i) {                  // P tile (f32 -> bf16)
      int idx = tid + i*256;
      int l = idx >> 4, m4 = idx & 15;
      f32x4 p = *(const f32x4*)&attn[((long)b*LSEQ + lt*128 + l)*LSEQ + mb*64 + m4*4];
      short4v s4;
      #pragma unroll
      for (int j = 0; j < 4; ++j) s4[j] = (short)bf16_rn(p[j]);
      int slot = m4 >> 1, half = m4 & 1;
      *(short4v*)&Ph[l*64 + ((slot ^ (l & 7)) << 3) + half*4] = s4;
    }
    __syncthreads();
    #pragma unroll
    for (int ks = 0; ks < 2; ++ks) {
      short8 bf[4];
      #pragma unroll
      for (int ni = 0; ni < 4; ++ni) {
        int cr = wc*64 + ni*16 + ln;
        bf[ni] = *(const short8*)&Ph[cr*64 + (((ks*4 + g) ^ (cr & 7)) << 3)];
      }
      #pragma unroll
      for (int mi = 0; mi < 4; ++mi) {
        int ar = wr*64 + mi*16 + ln;
        short8 af = *(const short8*)&Vh[ar*64 + (((ks*4 + g) ^ (ar & 7)) << 3)];
        #pragma unroll
        for (int ni = 0; ni < 4; ++ni)
          acc[mi][ni] = __builtin_amdgcn_mfma_f32_16x16x32_bf16(af, bf[ni], acc[mi][ni], 0,0,0);
      }
    }
  }
  __syncthreads();
  unsigned short* Tr = (unsigned short*)smem;      // [128 c][136]
  float gm = gamma[0];
  #pragma unroll
  for (int mi = 0; mi < 4; ++mi)
    #pragma unroll
    for (int ni = 0; ni < 4; ++ni)
      #pragma unroll
      for (int j = 0; j < 4; ++j) {
        int rloc = wr*64 + mi*16 + g*4 + j;
        int cloc = wc*64 + ni*16 + ln;
        Tr[rloc*136 + cloc] = bf16_rn(acc[mi][ni][j]);
      }
  __syncthreads();
  #pragma unroll
  for (int i = 0; i < 8; ++i) {
    int idx = tid + i*256;
    int c = idx >> 4, s = idx & 15;
    short8 v8 = *(const short8*)&Tr[c*136 + s*8];
    long base = ((long)b*C_IN + ct*128 + c)*LSEQ + lt*128 + s*8;
    f32x4 x0 = *(const f32x4*)&x[base];
    f32x4 x1 = *(const f32x4*)&x[base + 4];
    f32x4 o0, o1;
    #pragma unroll
    for (int j = 0; j < 4; ++j) {
      o0[j] = gm * bf16_to_f32((unsigned short)v8[j]) + x0[j];
      o1[j] = gm * bf16_to_f32((unsigned short)v8[j+4]) + x1[j];
    }
    *(f32x4*)&out[base] = o0;
    *(f32x4*)&out[base + 4] = o1;
  }
}

extern "C" void kernel_launch(void* const* d_in, const int* in_sizes, int n_in,
                              void* d_out, int out_size, void* d_ws, size_t ws_size,
                              hipStream_t stream)
{
  const float* x  = (const float*)d_in[0];
  const float* Wq = (const float*)d_in[1];
  const float* bq = (const float*)d_in[2];
  const float* Wk = (const float*)d_in[3];
  const float* bk = (const float*)d_in[4];
  const float* Wv = (const float*)d_in[5];
  const float* bv = (const float*)d_in[6];
  const float* gamma = (const float*)d_in[7];
  float* out  = (float*)d_out;
  float* attn = out + OUT_ELEMS;

  char* ws = (char*)d_ws;
  unsigned short* Wqh = (unsigned short*)(ws + 0);
  unsigned short* Wql = (unsigned short*)(ws + 65536);
  unsigned short* Wkh = (unsigned short*)(ws + 131072);
  unsigned short* Wkl = (unsigned short*)(ws + 196608);
  unsigned short* Wvh = (unsigned short*)(ws + 262144);
  unsigned short* qhp = (unsigned short*)(ws + 786432);
  unsigned short* qlp = (unsigned short*)(ws + 786432 + 1*4194304);
  unsigned short* khp = (unsigned short*)(ws + 786432 + 2*4194304);
  unsigned short* klp = (unsigned short*)(ws + 786432 + 3*4194304);
  unsigned short* vws = (unsigned short*)(ws + 786432 + 4*4194304);

  split_weights<<<320, 256, 0, stream>>>(Wq, Wk, Wv, Wqh, Wql, Wkh, Wkl, Wvh);
  qk_proj<<<dim3(16, B_SZ), 256, 0, stream>>>(x, Wqh, Wql, Wkh, Wkl, bq, bk, qhp, qlp, khp, klp);
  v_proj<<<dim3(8, 4, B_SZ), 256, 0, stream>>>(x, Wvh, bv, vws);
  energy_softmax<<<dim3(64, B_SZ), 256, 0, stream>>>(qhp, qlp, khp, klp, attn);
  pv_out<<<dim3(8, 4, B_SZ), 256, 0, stream>>>(vws, attn, x, gamma, out);
}

// Round 5
// 212.968 us; speedup vs baseline: 2.9240x; 1.5057x over previous
//
#include <hip/hip_runtime.h>

typedef __attribute__((ext_vector_type(8))) short short8;
typedef __attribute__((ext_vector_type(4))) short short4v;
typedef __attribute__((ext_vector_type(4))) float f32x4;

#define B_SZ 32
#define C_IN 512
#define C8V 64
#define LSEQ 1024
#define OUT_ELEMS (B_SZ * C_IN * LSEQ)

__device__ inline unsigned short bf16_rn(float f) {
  unsigned int u = __float_as_uint(f);
  unsigned int r = 0x7FFFu + ((u >> 16) & 1u);
  return (unsigned short)((u + r) >> 16);
}
__device__ inline float bf16_to_f32(unsigned short h) {
  return __uint_as_float(((unsigned int)h) << 16);
}
__device__ inline void split_bf16(float f, unsigned short &hi, unsigned short &lo) {
  hi = bf16_rn(f);
  lo = bf16_rn(f - bf16_to_f32(hi));
}

// ---------- Kernel 0: pre-split weights into bf16 hi/lo planes ----------
__global__ __launch_bounds__(256) void split_weights(
    const float* __restrict__ Wq, const float* __restrict__ Wk, const float* __restrict__ Wv,
    unsigned short* __restrict__ Wqh, unsigned short* __restrict__ Wql,
    unsigned short* __restrict__ Wkh, unsigned short* __restrict__ Wkl,
    unsigned short* __restrict__ Wvh)
{
  int i = (blockIdx.x * 256 + threadIdx.x) * 4;
  if (i < 262144) {
    f32x4 f = *(const f32x4*)&Wv[i];
    #pragma unroll
    for (int j = 0; j < 4; ++j) Wvh[i + j] = bf16_rn(f[j]);
  } else if (i < 294912) {
    int k = i - 262144;
    f32x4 f = *(const f32x4*)&Wq[k];
    #pragma unroll
    for (int j = 0; j < 4; ++j) { unsigned short h, l; split_bf16(f[j], h, l); Wqh[k+j] = h; Wql[k+j] = l; }
  } else {
    int k = i - 294912;
    f32x4 f = *(const f32x4*)&Wk[k];
    #pragma unroll
    for (int j = 0; j < 4; ++j) { unsigned short h, l; split_bf16(f[j], h, l); Wkh[k+j] = h; Wkl[k+j] = l; }
  }
}

// ---------- Kernel 1: q,k projection -> pre-split [b][l][64] hi/lo planes ----------
__global__ __launch_bounds__(256, 2) void qk_proj(
    const float* __restrict__ x,
    const unsigned short* __restrict__ Wqh, const unsigned short* __restrict__ Wql,
    const unsigned short* __restrict__ Wkh, const unsigned short* __restrict__ Wkl,
    const float* __restrict__ bq, const float* __restrict__ bk,
    unsigned short* __restrict__ qh, unsigned short* __restrict__ ql,
    unsigned short* __restrict__ kh, unsigned short* __restrict__ kl)
{
  const int nt = blockIdx.x;
  const int b  = blockIdx.y;
  const int tid = threadIdx.x;
  const int wave = tid >> 6, lane = tid & 63;
  const int wr = wave >> 1, wc = wave & 1;
  const int g = lane >> 4, ln = lane & 15;

  __shared__ char smem[66560];
  unsigned short* Ah = (unsigned short*)smem;
  unsigned short* Al = Ah + 128*64;
  unsigned short* Bh = Al + 128*64;
  unsigned short* Bl = Bh + 64*64;
  float* xs = (float*)(Bl + 64*64);

  f32x4 acc[4][2] = {};

  for (int kb = 0; kb < 8; ++kb) {
    if (kb) __syncthreads();
    #pragma unroll
    for (int i = 0; i < 4; ++i) {
      int idx = tid + i*256;
      int r = idx >> 3, jj = idx & 7;
      const unsigned short* sH = (r < 64) ? &Wqh[r*512 + kb*64 + jj*8]
                                          : &Wkh[(r-64)*512 + kb*64 + jj*8];
      const unsigned short* sL = (r < 64) ? &Wql[r*512 + kb*64 + jj*8]
                                          : &Wkl[(r-64)*512 + kb*64 + jj*8];
      int dst = r*64 + ((jj ^ (r & 7)) << 3);
      *(short8*)&Ah[dst] = *(const short8*)sH;
      *(short8*)&Al[dst] = *(const short8*)sL;
    }
    #pragma unroll
    for (int i = 0; i < 4; ++i) {
      int idx = tid + i*256;
      int kk = idx >> 4, l4 = idx & 15;
      f32x4 v = *(const f32x4*)&x[((long)b*C_IN + kb*64 + kk)*LSEQ + nt*64 + l4*4];
      *(f32x4*)&xs[kk*68 + l4*4] = v;
    }
    __syncthreads();
    {
      int l = tid & 63, kc = (tid >> 6) * 16;
      unsigned short hbuf[16], lbuf[16];
      #pragma unroll
      for (int i = 0; i < 16; ++i) split_bf16(xs[(kc + i)*68 + l], hbuf[i], lbuf[i]);
      #pragma unroll
      for (int s2 = 0; s2 < 2; ++s2) {
        int s = (kc >> 3) + s2;
        int dst = l*64 + ((s ^ (l & 7)) << 3);
        *(short8*)&Bh[dst] = *(const short8*)&hbuf[s2*8];
        *(short8*)&Bl[dst] = *(const short8*)&lbuf[s2*8];
      }
    }
    __syncthreads();
    #pragma unroll
    for (int ks = 0; ks < 2; ++ks) {
      short8 bhf[2], blf[2];
      #pragma unroll
      for (int ni = 0; ni < 2; ++ni) {
        int cr = wc*32 + ni*16 + ln;
        int s = ((ks*4 + g) ^ (cr & 7)) << 3;
        bhf[ni] = *(const short8*)&Bh[cr*64 + s];
        blf[ni] = *(const short8*)&Bl[cr*64 + s];
      }
      #pragma unroll
      for (int mi = 0; mi < 4; ++mi) {
        int ar = wr*64 + mi*16 + ln;
        int s = ((ks*4 + g) ^ (ar & 7)) << 3;
        short8 ahf = *(const short8*)&Ah[ar*64 + s];
        short8 alf = *(const short8*)&Al[ar*64 + s];
        #pragma unroll
        for (int ni = 0; ni < 2; ++ni) {
          acc[mi][ni] = __builtin_amdgcn_mfma_f32_16x16x32_bf16(ahf, bhf[ni], acc[mi][ni], 0,0,0);
          acc[mi][ni] = __builtin_amdgcn_mfma_f32_16x16x32_bf16(ahf, blf[ni], acc[mi][ni], 0,0,0);
          acc[mi][ni] = __builtin_amdgcn_mfma_f32_16x16x32_bf16(alf, bhf[ni], acc[mi][ni], 0,0,0);
        }
      }
    }
  }
  __syncthreads();
  unsigned short* Trh = (unsigned short*)smem;
  unsigned short* Trl = Trh + 64*136;
  #pragma unroll
  for (int mi = 0; mi < 4; ++mi)
    #pragma unroll
    for (int ni = 0; ni < 2; ++ni)
      #pragma unroll
      for (int j = 0; j < 4; ++j) {
        int rloc = wr*64 + mi*16 + g*4 + j;
        int cloc = wc*32 + ni*16 + ln;
        float bias = (rloc < 64) ? bq[rloc] : bk[rloc - 64];
        unsigned short hi, lo; split_bf16(acc[mi][ni][j] + bias, hi, lo);
        Trh[cloc*136 + rloc] = hi;
        Trl[cloc*136 + rloc] = lo;
      }
  __syncthreads();
  #pragma unroll
  for (int i = 0; i < 4; ++i) {
    int idx = tid + i*256;
    int l = idx >> 4, s = idx & 15;
    long row = ((long)b*LSEQ + nt*64 + l) * 64;
    short8 h  = *(const short8*)&Trh[l*136 + s*8];
    short8 lo = *(const short8*)&Trl[l*136 + s*8];
    if (s < 8) { *(short8*)&qh[row + s*8] = h;      *(short8*)&ql[row + s*8] = lo; }
    else       { *(short8*)&kh[row + (s-8)*8] = h;  *(short8*)&kl[row + (s-8)*8] = lo; }
  }
}

// ---------- Kernel 2: v projection -> bf16 [b][c][l] ----------
__global__ __launch_bounds__(256, 2) void v_proj(
    const float* __restrict__ x,
    const unsigned short* __restrict__ Wvh,
    const float* __restrict__ bv,
    unsigned short* __restrict__ vws)
{
  const int lt = blockIdx.x;
  const int ct = blockIdx.y;
  const int b  = blockIdx.z;
  const int tid = threadIdx.x;
  const int wave = tid >> 6, lane = tid & 63;
  const int wr = wave >> 1, wc = wave & 1;
  const int g = lane >> 4, ln = lane & 15;

  __shared__ char smem[66560];
  unsigned short* Ahs = (unsigned short*)smem;
  unsigned short* Bhs = Ahs + 8192;
  float* xs = (float*)(Bhs + 8192);

  f32x4 acc[4][4] = {};

  for (int kb = 0; kb < 8; ++kb) {
    if (kb) __syncthreads();
    #pragma unroll
    for (int i = 0; i < 4; ++i) {
      int idx = tid + i*256;
      int r = idx >> 3, jj = idx & 7;
      *(short8*)&Ahs[r*64 + ((jj ^ (r & 7)) << 3)] =
        *(const short8*)&Wvh[(ct*128 + r)*512 + kb*64 + jj*8];
    }
    #pragma unroll
    for (int i = 0; i < 8; ++i) {
      int idx = tid + i*256;
      int kk = idx >> 5, l4 = idx & 31;
      f32x4 v = *(const f32x4*)&x[((long)b*C_IN + kb*64 + kk)*LSEQ + lt*128 + l4*4];
      *(f32x4*)&xs[kk*132 + l4*4] = v;
    }
    __syncthreads();
    {
      int l = tid & 127, kc = (tid >> 7) * 32;
      unsigned short hbuf[32];
      #pragma unroll
      for (int i = 0; i < 32; ++i) hbuf[i] = bf16_rn(xs[(kc + i)*132 + l]);
      #pragma unroll
      for (int s2 = 0; s2 < 4; ++s2) {
        int s = (kc >> 3) + s2;
        *(short8*)&Bhs[l*64 + ((s ^ (l & 7)) << 3)] = *(const short8*)&hbuf[s2*8];
      }
    }
    __syncthreads();
    #pragma unroll
    for (int ks = 0; ks < 2; ++ks) {
      short8 bf[4];
      #pragma unroll
      for (int ni = 0; ni < 4; ++ni) {
        int cr = wc*64 + ni*16 + ln;
        bf[ni] = *(const short8*)&Bhs[cr*64 + (((ks*4 + g) ^ (cr & 7)) << 3)];
      }
      #pragma unroll
      for (int mi = 0; mi < 4; ++mi) {
        int ar = wr*64 + mi*16 + ln;
        short8 af = *(const short8*)&Ahs[ar*64 + (((ks*4 + g) ^ (ar & 7)) << 3)];
        #pragma unroll
        for (int ni = 0; ni < 4; ++ni)
          acc[mi][ni] = __builtin_amdgcn_mfma_f32_16x16x32_bf16(af, bf[ni], acc[mi][ni], 0,0,0);
      }
    }
  }
  __syncthreads();
  unsigned short* Tr = (unsigned short*)smem;
  #pragma unroll
  for (int mi = 0; mi < 4; ++mi)
    #pragma unroll
    for (int ni = 0; ni < 4; ++ni)
      #pragma unroll
      for (int j = 0; j < 4; ++j) {
        int rloc = wr*64 + mi*16 + g*4 + j;
        int cloc = wc*64 + ni*16 + ln;
        Tr[rloc*136 + cloc] = bf16_rn(acc[mi][ni][j] + bv[ct*128 + rloc]);
      }
  __syncthreads();
  #pragma unroll
  for (int i = 0; i < 8; ++i) {
    int idx = tid + i*256;
    int c = idx >> 4, s = idx & 15;
    *(short8*)&vws[((long)b*C_IN + ct*128 + c)*LSEQ + lt*128 + s*8] =
      *(const short8*)&Tr[c*136 + s*8];
  }
}

// ---------- Kernel 3: energy + softmax -> attn f32 (d_out) + P bf16 copy ----------
__global__ __launch_bounds__(256, 2) void energy_softmax(
    const unsigned short* __restrict__ qh, const unsigned short* __restrict__ ql,
    const unsigned short* __restrict__ kh, const unsigned short* __restrict__ kl,
    float* __restrict__ attn, unsigned short* __restrict__ pbuf)
{
  const int lt = blockIdx.x;
  const int b  = blockIdx.y;
  const int tid = threadIdx.x;
  const int wave = tid >> 6, lane = tid & 63;
  const int g = lane >> 4, ln = lane & 15;

  __shared__ unsigned short Ksm[16640];   // Kh[8192] + Kl[8192]; reused as Pb[16][1032]
  __shared__ float redM[4][16];
  __shared__ float redS[4][16];
  unsigned short* Kh = Ksm;
  unsigned short* Kl = Ksm + 8192;

  // Q fragments (pre-split bf16, [b][l][64])
  short8 ah[2], al[2];
  {
    long qrow = ((long)b*LSEQ + lt*16 + ln) * 64;
    #pragma unroll
    for (int ks = 0; ks < 2; ++ks) {
      ah[ks] = *(const short8*)&qh[qrow + ks*32 + g*8];
      al[ks] = *(const short8*)&ql[qrow + ks*32 + g*8];
    }
  }

  // staging geometry: rows rb + j*32, 16B slot jj; LDS slot jj^(rb&7)
  const int rb = tid >> 3, jj = tid & 7;
  const int dst0 = rb*64 + ((jj ^ (rb & 7)) << 3);
  const long kbase = ((long)b*LSEQ + rb)*64 + jj*8;

  short8 rkh[4], rkl[4];
  #pragma unroll
  for (int j = 0; j < 4; ++j) {          // prefetch chunk 0
    rkh[j] = *(const short8*)&kh[kbase + j*2048];
    rkl[j] = *(const short8*)&kl[kbase + j*2048];
  }

  f32x4 acc[8][2] = {};
  #pragma unroll
  for (int c = 0; c < 8; ++c) {
    __syncthreads();                     // waits prefetched loads + prior reads done
    #pragma unroll
    for (int j = 0; j < 4; ++j) {
      *(short8*)&Kh[dst0 + j*2048] = rkh[j];
      *(short8*)&Kl[dst0 + j*2048] = rkl[j];
    }
    __syncthreads();
    if (c < 7) {
      #pragma unroll
      for (int j = 0; j < 4; ++j) {      // issue next chunk (overlaps MFMA below)
        rkh[j] = *(const short8*)&kh[kbase + (long)(c+1)*8192 + j*2048];
        rkl[j] = *(const short8*)&kl[kbase + (long)(c+1)*8192 + j*2048];
      }
    }
    #pragma unroll
    for (int fq = 0; fq < 2; ++fq) {
      int mloc = wave*32 + fq*16 + ln;
      #pragma unroll
      for (int ks = 0; ks < 2; ++ks) {
        int s = ((ks*4 + g) ^ (mloc & 7)) << 3;
        short8 bh = *(const short8*)&Kh[mloc*64 + s];
        short8 bl = *(const short8*)&Kl[mloc*64 + s];
        acc[c][fq] = __builtin_amdgcn_mfma_f32_16x16x32_bf16(ah[ks], bh, acc[c][fq], 0,0,0);
        acc[c][fq] = __builtin_amdgcn_mfma_f32_16x16x32_bf16(ah[ks], bl, acc[c][fq], 0,0,0);
        acc[c][fq] = __builtin_amdgcn_mfma_f32_16x16x32_bf16(al[ks], bh, acc[c][fq], 0,0,0);
      }
    }
  }

  // --- row softmax ---
  float mx[4];
  #pragma unroll
  for (int j = 0; j < 4; ++j) {
    float m = -1e30f;
    #pragma unroll
    for (int c = 0; c < 8; ++c)
      #pragma unroll
      for (int fq = 0; fq < 2; ++fq) m = fmaxf(m, acc[c][fq][j]);
    #pragma unroll
    for (int off = 1; off < 16; off <<= 1) m = fmaxf(m, __shfl_xor(m, off));
    mx[j] = m;
  }
  if (ln == 0) {
    #pragma unroll
    for (int j = 0; j < 4; ++j) redM[wave][g*4+j] = mx[j];
  }
  __syncthreads();
  #pragma unroll
  for (int j = 0; j < 4; ++j) {
    float m = redM[0][g*4+j];
    #pragma unroll
    for (int w = 1; w < 4; ++w) m = fmaxf(m, redM[w][g*4+j]);
    mx[j] = m;
  }
  float sm[4];
  #pragma unroll
  for (int j = 0; j < 4; ++j) {
    float s = 0.f;
    #pragma unroll
    for (int c = 0; c < 8; ++c)
      #pragma unroll
      for (int fq = 0; fq < 2; ++fq) {
        float p = expf(acc[c][fq][j] - mx[j]);
        acc[c][fq][j] = p;
        s += p;
      }
    #pragma unroll
    for (int off = 1; off < 16; off <<= 1) s += __shfl_xor(s, off);
    sm[j] = s;
  }
  if (ln == 0) {
    #pragma unroll
    for (int j = 0; j < 4; ++j) redS[wave][g*4+j] = sm[j];
  }
  __syncthreads();
  #pragma unroll
  for (int j = 0; j < 4; ++j) {
    float s = redS[0][g*4+j];
    #pragma unroll
    for (int w = 1; w < 4; ++w) s += redS[w][g*4+j];
    sm[j] = 1.0f / s;
  }

  // --- epilogue: transpose bf16(P) into LDS, then coalesced attn f32 + pbuf bf16 ---
  unsigned short* Pb = Ksm;              // [16][1032]
  __syncthreads();
  #pragma unroll
  for (int c = 0; c < 8; ++c)
    #pragma unroll
    for (int fq = 0; fq < 2; ++fq) {
      int m0 = c*128 + wave*32 + fq*16 + ln;
      #pragma unroll
      for (int j = 0; j < 4; ++j)
        Pb[(g*4+j)*1032 + m0] = bf16_rn(acc[c][fq][j] * sm[j]);
    }
  __syncthreads();
  #pragma unroll
  for (int u = 0; u < 8; ++u) {
    int cid = tid + u*256;
    int row = cid >> 7, col = (cid & 127) * 8;
    short8 v = *(const short8*)&Pb[row*1032 + col];
    long gro = ((long)b*LSEQ + lt*16 + row)*LSEQ + col;
    *(short8*)&pbuf[gro] = v;
    f32x4 f0, f1;
    #pragma unroll
    for (int i = 0; i < 4; ++i) {
      f0[i] = bf16_to_f32((unsigned short)v[i]);
      f1[i] = bf16_to_f32((unsigned short)v[i+4]);
    }
    *(f32x4*)&attn[gro] = f0;
    *(f32x4*)&attn[gro + 4] = f1;
  }
}

// ---------- Kernel 4: out = gamma * (V @ P^T) + x ----------
__global__ __launch_bounds__(256, 2) void pv_out(
    const unsigned short* __restrict__ vws,
    const unsigned short* __restrict__ pbuf,
    const float* __restrict__ x,
    const float* __restrict__ gamma,
    float* __restrict__ out)
{
  const int lt = blockIdx.x;
  const int ct = blockIdx.y;
  const int b  = blockIdx.z;
  const int tid = threadIdx.x;
  const int wave = tid >> 6, lane = tid & 63;
  const int wr = wave >> 1, wc = wave & 1;
  const int g = lane >> 4, ln = lane & 15;

  __shared__ char smem[34816];
  unsigned short* Vh = (unsigned short*)smem;      // [128][64] swizzled
  unsigned short* Ph = Vh + 8192;                  // [128][64] swizzled

  const int rb = tid >> 3, jj = tid & 7;
  const int dst0 = rb*64 + ((jj ^ (rb & 7)) << 3);
  const long vbase = ((long)(b*C_IN + ct*128) + rb)*LSEQ + jj*8;
  const long pbase = ((long)b*LSEQ + lt*128 + rb)*LSEQ + jj*8;

  f32x4 acc[4][4] = {};
  short8 rv[4], rp[4];
  #pragma unroll
  for (int j = 0; j < 4; ++j) {          // prefetch tile 0
    rv[j] = *(const short8*)&vws[vbase + (long)j*32*LSEQ];
    rp[j] = *(const short8*)&pbuf[pbase + (long)j*32*LSEQ];
  }

  for (int mb = 0; mb < 16; ++mb) {
    __syncthreads();                     // waits prefetched loads + prior reads done
    #pragma unroll
    for (int j = 0; j < 4; ++j) {
      *(short8*)&Vh[dst0 + j*2048] = rv[j];
      *(short8*)&Ph[dst0 + j*2048] = rp[j];
    }
    __syncthreads();
    if (mb < 15) {
      #pragma unroll
      for (int j = 0; j < 4; ++j) {      // issue next tile (overlaps MFMA below)
        rv[j] = *(const short8*)&vws[vbase + (mb+1)*64 + (long)j*32*LSEQ];
        rp[j] = *(const short8*)&pbuf[pbase + (mb+1)*64 + (long)j*32*LSEQ];
      }
    }
    #pragma unroll
    for (int ks = 0; ks < 2; ++ks) {
      short8 bf[4];
      #pragma unroll
      for (int ni = 0; ni < 4; ++ni) {
        int cr = wc*64 + ni*16 + ln;
        bf[ni] = *(const short8*)&Ph[cr*64 + (((ks*4 + g) ^ (cr & 7)) << 3)];
      }
      #pragma unroll
      for (int mi = 0; mi < 4; ++mi) {
        int ar = wr*64 + mi*16 + ln;
        short8 af = *(const short8*)&Vh[ar*64 + (((ks*4 + g) ^ (ar & 7)) << 3)];
        #pragma unroll
        for (int ni = 0; ni < 4; ++ni)
          acc[mi][ni] = __builtin_amdgcn_mfma_f32_16x16x32_bf16(af, bf[ni], acc[mi][ni], 0,0,0);
      }
    }
  }
  __syncthreads();
  unsigned short* Tr = (unsigned short*)smem;      // [128 c][136]
  float gm = gamma[0];
  #pragma unroll
  for (int mi = 0; mi < 4; ++mi)
    #pragma unroll
    for (int ni = 0; ni < 4; ++ni)
      #pragma unroll
      for (int j = 0; j < 4; ++j) {
        int rloc = wr*64 + mi*16 + g*4 + j;
        int cloc = wc*64 + ni*16 + ln;
        Tr[rloc*136 + cloc] = bf16_rn(acc[mi][ni][j]);
      }
  __syncthreads();
  #pragma unroll
  for (int i = 0; i < 8; ++i) {
    int idx = tid + i*256;
    int c = idx >> 4, s = idx & 15;
    short8 v8 = *(const short8*)&Tr[c*136 + s*8];
    long base = ((long)b*C_IN + ct*128 + c)*LSEQ + lt*128 + s*8;
    f32x4 x0 = *(const f32x4*)&x[base];
    f32x4 x1 = *(const f32x4*)&x[base + 4];
    f32x4 o0, o1;
    #pragma unroll
    for (int j = 0; j < 4; ++j) {
      o0[j] = gm * bf16_to_f32((unsigned short)v8[j]) + x0[j];
      o1[j] = gm * bf16_to_f32((unsigned short)v8[j+4]) + x1[j];
    }
    *(f32x4*)&out[base] = o0;
    *(f32x4*)&out[base + 4] = o1;
  }
}

extern "C" void kernel_launch(void* const* d_in, const int* in_sizes, int n_in,
                              void* d_out, int out_size, void* d_ws, size_t ws_size,
                              hipStream_t stream)
{
  const float* x  = (const float*)d_in[0];
  const float* Wq = (const float*)d_in[1];
  const float* bq = (const float*)d_in[2];
  const float* Wk = (const float*)d_in[3];
  const float* bk = (const float*)d_in[4];
  const float* Wv = (const float*)d_in[5];
  const float* bv = (const float*)d_in[6];
  const float* gamma = (const float*)d_in[7];
  float* out  = (float*)d_out;
  float* attn = out + OUT_ELEMS;

  char* ws = (char*)d_ws;
  unsigned short* Wqh = (unsigned short*)(ws + 0);
  unsigned short* Wql = (unsigned short*)(ws + 65536);
  unsigned short* Wkh = (unsigned short*)(ws + 131072);
  unsigned short* Wkl = (unsigned short*)(ws + 196608);
  unsigned short* Wvh = (unsigned short*)(ws + 262144);
  unsigned short* qhp = (unsigned short*)(ws + 786432);
  unsigned short* qlp = (unsigned short*)(ws + 786432 + 1ul*4194304);
  unsigned short* khp = (unsigned short*)(ws + 786432 + 2ul*4194304);
  unsigned short* klp = (unsigned short*)(ws + 786432 + 3ul*4194304);
  unsigned short* vws = (unsigned short*)(ws + 786432 + 4ul*4194304);
  unsigned short* pbuf = (unsigned short*)(ws + 786432 + 4ul*4194304 + 33554432);

  split_weights<<<320, 256, 0, stream>>>(Wq, Wk, Wv, Wqh, Wql, Wkh, Wkl, Wvh);
  qk_proj<<<dim3(16, B_SZ), 256, 0, stream>>>(x, Wqh, Wql, Wkh, Wkl, bq, bk, qhp, qlp, khp, klp);
  v_proj<<<dim3(8, 4, B_SZ), 256, 0, stream>>>(x, Wvh, bv, vws);
  energy_softmax<<<dim3(64, B_SZ), 256, 0, stream>>>(qhp, qlp, khp, klp, attn, pbuf);
  pv_out<<<dim3(8, 4, B_SZ), 256, 0, stream>>>(vws, pbuf, x, gamma, out);
}